// Round 1
// baseline (757.618 us; speedup 1.0000x reference)
//
#include <hip/hip_runtime.h>
#include <hip/hip_fp16.h>

#define NS 576          // samples per ray (384 inner + 192 outer)
#define CHUNKS 9        // 576 / 64
#define RAYS_PER_BLOCK 4

__global__ __launch_bounds__(256) void nerf_render_kernel(
    const float* __restrict__ sigmas,   // [N, S]
    const float* __restrict__ rgbs,     // [N, S, 3]
    const float* __restrict__ bg,       // [3]
    float* __restrict__ img,            // [N, 3]
    float* __restrict__ invd,           // [N]
    float* __restrict__ wout,           // [N, S]
    float* __restrict__ zlout,          // [N, S]
    int N)
{
    __shared__ float s_z[NS];
    __shared__ float s_delta[NS];
    __shared__ float s_invz[NS];
    __shared__ float s_zlog[NS];

    const int tid = threadIdx.x;

    // ---- Build z tables once per block (matches jnp.linspace / 10**x / fp16 round-trip) ----
    for (int s = tid; s < NS; s += 256) {
        float zl;
        if (s < 384) {
            const float start = (float)(-1.3010299956639813);            // log10(0.05)
            const float stop  = (float)(-1.3010299956639813 / 384.0);    // a/384
            const float step  = (stop - start) / 383.0f;
            zl = start + (float)s * step;
        } else {
            const float stop = (float)(2.0 - 2.0 / 192.0);               // 1.98958333...
            const float step = stop / 191.0f;
            zl = (float)(s - 384) * step;
        }
        // z_vals = fp32(fp16(10^zl))  (reference quantizes z_vals to fp16)
        float z = __half2float(__float2half_rn(exp10f(zl)));
        s_zlog[s] = zl;
        s_z[s]    = z;
    }
    __syncthreads();
    for (int s = tid; s < NS; s += 256) {
        float z = s_z[s];
        s_delta[s] = (s == NS - 1) ? 1e10f : (s_z[s + 1] - z);
        s_invz[s]  = 1.0f / z;
    }
    __syncthreads();

    const int wave = tid >> 6;
    const int lane = tid & 63;
    const int ray  = blockIdx.x * RAYS_PER_BLOCK + wave;
    if (ray >= N) return;

    const float* __restrict__ sig = sigmas + (size_t)ray * NS;
    const float* __restrict__ rgb = rgbs   + (size_t)ray * NS * 3;
    float* __restrict__ wrow = wout  + (size_t)ray * NS;
    float* __restrict__ zrow = zlout + (size_t)ray * NS;

    float T = 1.0f;                    // running exclusive transmittance carry
    float a0 = 0.f, a1 = 0.f, a2 = 0.f;
    float id = 0.f, wsum = 0.f;

    #pragma unroll
    for (int c = 0; c < CHUNKS; ++c) {
        const int s = c * 64 + lane;
        const float sigma = sig[s];
        const float delta = s_delta[s];
        const float invz  = s_invz[s];
        const float zl    = s_zlog[s];

        const float e     = expf(-sigma * delta);
        const float alpha = 1.0f - e;
        float P = e + 1e-10f;          // (1 - alpha + eps) factor

        // inclusive multiplicative scan over the 64-lane wave
        #pragma unroll
        for (int off = 1; off < 64; off <<= 1) {
            float v = __shfl_up(P, off);
            if (lane >= off) P *= v;
        }

        const float prev = __shfl_up(P, 1);
        const float ex   = (lane == 0) ? T : T * prev;   // exclusive transmittance
        const float w    = alpha * ex;

        wrow[s] = w;
        zrow[s] = zl;

        const float r0 = rgb[3 * s + 0];
        const float r1 = rgb[3 * s + 1];
        const float r2 = rgb[3 * s + 2];
        a0 = fmaf(w, r0, a0);
        a1 = fmaf(w, r1, a1);
        a2 = fmaf(w, r2, a2);
        id = fmaf(w, invz, id);
        wsum += w;

        T *= __shfl(P, 63);            // carry full-chunk product
    }

    // wave-level reductions
    #pragma unroll
    for (int off = 32; off > 0; off >>= 1) {
        a0   += __shfl_down(a0, off);
        a1   += __shfl_down(a1, off);
        a2   += __shfl_down(a2, off);
        id   += __shfl_down(id, off);
        wsum += __shfl_down(wsum, off);
    }

    if (lane == 0) {
        const float rem = 1.0f - wsum;
        img[(size_t)ray * 3 + 0] = fmaf(rem, bg[0], a0);
        img[(size_t)ray * 3 + 1] = fmaf(rem, bg[1], a1);
        img[(size_t)ray * 3 + 2] = fmaf(rem, bg[2], a2);
        invd[ray] = id;
    }
}

extern "C" void kernel_launch(void* const* d_in, const int* in_sizes, int n_in,
                              void* d_out, int out_size, void* d_ws, size_t ws_size,
                              hipStream_t stream) {
    // inputs: rays_o [N,3], rays_d [N,3], bg_color [3], sigmas [N,S], rgbs [N,S,3]
    const int N = in_sizes[0] / 3;
    const float* sigmas = (const float*)d_in[3];
    const float* rgbs   = (const float*)d_in[4];
    const float* bg     = (const float*)d_in[2];

    // outputs concatenated: image [N,3], invdepth [N], weights [N,S], z_vals_log [N,S]
    float* out   = (float*)d_out;
    float* img   = out;
    float* invd  = out + (size_t)3 * N;
    float* wout  = out + (size_t)4 * N;
    float* zlout = out + (size_t)4 * N + (size_t)N * NS;

    const int blocks = (N + RAYS_PER_BLOCK - 1) / RAYS_PER_BLOCK;
    nerf_render_kernel<<<blocks, 256, 0, stream>>>(sigmas, rgbs, bg, img, invd,
                                                   wout, zlout, N);
}